// Round 9
// baseline (193.172 us; speedup 1.0000x reference)
//
#include <hip/hip_runtime.h>
#include <hip/hip_cooperative_groups.h>
#include <stdint.h>
#include <math.h>

// Must match numpy's unfused fp32 ops exactly: no FMA contraction in this TU.
#pragma clang fp contract(off)

namespace cg = cooperative_groups;

#define N        8192
#define NCHUNK   128      // N / 64
#define NTILE    64       // scan: 2 chunks per tile
#define MAX_OUT  300

__device__ __forceinline__ uint64_t rl64(uint64_t v, int l) {
    uint32_t lo = (uint32_t)__builtin_amdgcn_readlane((int)(uint32_t)v, l);
    uint32_t hi = (uint32_t)__builtin_amdgcn_readlane((int)(uint32_t)(v >> 32), l);
    return ((uint64_t)hi << 32) | lo;
}
__device__ __forceinline__ float rlf(float v, int l) {
    return __uint_as_float((uint32_t)__builtin_amdgcn_readlane((int)__float_as_uint(v), l));
}
// word of packed row j (two rows per lane): lane j>>1, half j&1
__device__ __forceinline__ uint64_t rlsel(uint64_t v0, uint64_t v1, int j) {
    uint64_t a = rl64(v0, j >> 1);
    uint64_t b = rl64(v1, j >> 1);
    return (j & 1) ? b : a;
}

// ---------------------------------------------------------------------------
// ONE cooperative kernel: rank+scatter -> grid.sync -> mask -> grid.sync ->
// scan (block 0). Eliminates ~2 launch gaps (~10 us each) + kernel tails.
// ---------------------------------------------------------------------------
__global__ void __launch_bounds__(1024)
nms_all(const float4* __restrict__ rois,
        const float*  __restrict__ scores,
        float4* __restrict__ sboxes,
        int*    __restrict__ sidx,
        uint64_t* __restrict__ maskT,
        int*    __restrict__ out) {
    // phase-1 LDS
    __shared__ uint32_t sk[N];                   // 32 KB score keys
    // phase-3 LDS (block 0 only; ~11.5 KB)
    __shared__ uint32_t removed32[2 * NCHUNK];
    __shared__ uint64_t pf[2][7][64];            // dbuf: D0,D1,X,Y0a,Y0b,Y1a,Y1b
    __shared__ uint64_t s_kmask[NCHUNK];
    __shared__ int      s_kbase[NCHUNK];
    __shared__ int      s_klist[2][128];
    __shared__ int      s_k[2];
    __shared__ int      s_kept, s_done, s_nch;

    const int t    = threadIdx.x;
    const int lane = t & 63;
    const int wave = t >> 6;
    const int b    = blockIdx.x;

    // ================= phase 1: rank + scatter =================
    {
        const uint4* g4 = (const uint4*)scores;
        uint4* s4 = (uint4*)sk;
        for (int q = t; q < N / 4; q += 1024) s4[q] = g4[q];
    }
    __syncthreads();
    {
        const int il = t >> 5;        // box-in-block 0..31 (half-wave granule)
        const int g  = t & 31;        // stripe 0..31
        const int i  = b * 32 + il;
        const uint32_t my = sk[i];    // scores >= 0 -> uint-monotonic
        int cnt = 0;
        const uint4* k4 = (const uint4*)sk;
        for (int k = 0; k < 64; ++k) {
            int q = k * 32 + g;       // contiguous 512B per half-wave: conflict-free
            uint4 v = k4[q];
            int j0 = q * 4;
            cnt += (v.x > my) || (v.x == my && (j0 + 0) < i);
            cnt += (v.y > my) || (v.y == my && (j0 + 1) < i);
            cnt += (v.z > my) || (v.z == my && (j0 + 2) < i);
            cnt += (v.w > my) || (v.w == my && (j0 + 3) < i);
        }
        // half-wave reduction over g (xor masks <32 stay within 32-lane halves)
        cnt += __shfl_xor(cnt, 16, 64);
        cnt += __shfl_xor(cnt, 8, 64);
        cnt += __shfl_xor(cnt, 4, 64);
        cnt += __shfl_xor(cnt, 2, 64);
        cnt += __shfl_xor(cnt, 1, 64);
        if (g == 0) {                 // unique keys -> ranks are a permutation
            sboxes[cnt] = rois[i];
            sidx[cnt]   = i;
        }
    }
    cg::this_grid().sync();

    // ================= phase 2: suppression mask =================
    // one 64x64 tile per wave; row boxes broadcast via v_readlane (no LDS).
    // Exact f64 compare == fp32 IEEE div vs 0.5:
    //   fl32(i/d) > 0.5  <=>  2i > d*(1+2^-24)   (product exact: 24+25 <= 53 bits)
    {
        const int wv = (b << 4) | wave;            // 0..4095
        const double C = 1.0 + 0x1p-24;
        for (int L = wv; L < 8256; L += 4096) {
            int bi = (int)(128.5 - sqrt(16512.25 - 2.0 * (double)L));
            if (bi < 0) bi = 0;
            if (bi > 127) bi = 127;
            while (bi < 127 && (bi + 1) * 128 - ((bi + 1) * bi) / 2 <= L) ++bi;
            while (bi > 0 && bi * 128 - (bi * (bi - 1)) / 2 > L) --bi;
            const int bj = bi + (L - (bi * 128 - (bi * (bi - 1)) / 2));

            const float4 cb = sboxes[bj * 64 + lane];      // column box (regs)
            const float  ac = (cb.z - cb.x) * (cb.w - cb.y);
            const float4 rv = sboxes[bi * 64 + lane];      // row box, lane r holds row r
            const float  av = (rv.z - rv.x) * (rv.w - rv.y);
            const bool diag = (bi == bj);

            uint64_t myword = 0;
            for (int r = 0; r < 64; ++r) {
                float bx = rlf(rv.x, r), by = rlf(rv.y, r);
                float bz = rlf(rv.z, r), bw = rlf(rv.w, r);
                float ar = rlf(av, r);
                float lx    = fmaxf(bx, cb.x);
                float ly    = fmaxf(by, cb.y);
                float hx    = fminf(bz, cb.z);
                float hy    = fminf(bw, cb.w);
                float w     = fmaxf(hx - lx, 0.0f);
                float h     = fmaxf(hy - ly, 0.0f);
                float inter = w * h;
                float denom = (ar + ac) - inter;           // left-to-right like numpy
                double di = (double)inter, dd = (double)denom;
                bool sup = (di + di) > (dd * C);
                uint64_t word = __ballot(sup);
                if (diag)
                    word &= (r == 63) ? 0ull : (~0ull << (r + 1));
                myword = (lane == r) ? word : myword;
            }
            maskT[(size_t)bj * N + bi * 64 + lane] = myword;   // 512B coalesced
        }
    }
    cg::this_grid().sync();

    // ================= phase 3: greedy scan (block 0) =================
    // R5-design (benched fast in R6): 64 tiles x 2 chunks, ONE barrier/tile.
    if (b != 0) return;

    if (t < 2 * NCHUNK) removed32[t] = 0;
    if (t == 0) { s_kept = 0; s_done = 0; s_nch = 0; s_k[0] = 0; s_k[1] = 0; }
    if (wave == 1) {                             // prefetch tile 0 into pf[0]
        pf[0][0][lane] = maskT[(size_t)0 * N + 0 * 64 + lane];   // D0
        pf[0][1][lane] = maskT[(size_t)1 * N + 1 * 64 + lane];   // D1
        pf[0][2][lane] = maskT[(size_t)1 * N + 0 * 64 + lane];   // X
        pf[0][3][lane] = maskT[(size_t)2 * N + 0 * 64 + lane];   // Y0a
        pf[0][4][lane] = maskT[(size_t)2 * N + 1 * 64 + lane];   // Y0b
        pf[0][5][lane] = maskT[(size_t)3 * N + 0 * 64 + lane];   // Y1a
        pf[0][6][lane] = maskT[(size_t)3 * N + 1 * 64 + lane];   // Y1b
    }
    __syncthreads();

    int kept = 0;                                // wave0-uniform mirror of s_kept
    for (int it = 0; it < NTILE; ++it) {
        const int c0 = 2 * it, c1 = 2 * it + 1;
        const int buf = it & 1;

        if (wave == 0) {
            // ---- A: resolve tile it ----
            uint64_t D0  = pf[buf][0][lane], D1  = pf[buf][1][lane];
            uint64_t X   = pf[buf][2][lane];
            uint64_t Y0a = pf[buf][3][lane], Y0b = pf[buf][4][lane];
            uint64_t Y1a = pf[buf][5][lane], Y1b = pf[buf][6][lane];
            uint64_t rem0 = (uint64_t)removed32[2 * c0] | ((uint64_t)removed32[2 * c0 + 1] << 32);
            uint64_t rem1 = (uint64_t)removed32[2 * c1] | ((uint64_t)removed32[2 * c1 + 1] << 32);
            uint64_t keep0 = 0, keep1 = 0, xw = 0, y0 = 0, y1 = 0;

            uint64_t cand = ~rem0;                 // chunk c0 greedy chain
            while (cand) {
                int l = __builtin_ctzll(cand);
                keep0 |= (1ull << l);
                uint64_t d = rl64(D0, l);
                xw |= rl64(X, l);
                y0 |= rl64(Y0a, l);
                y1 |= rl64(Y1a, l);
                cand &= ~d;
                cand &= ~(1ull << l);
            }
            rem1 |= xw;
            cand = ~rem1;                          // chunk c1 greedy chain
            while (cand) {
                int l = __builtin_ctzll(cand);
                keep1 |= (1ull << l);
                uint64_t d = rl64(D1, l);
                y0 |= rl64(Y0b, l);
                y1 |= rl64(Y1b, l);
                cand &= ~d;
                cand &= ~(1ull << l);
            }
            // fold urgent removed-updates for next tile (atomic: B also writes)
            if (c0 + 2 < NCHUNK && y0) {
                atomicOr(&removed32[2 * (c0 + 2)],     (uint32_t)y0);
                atomicOr(&removed32[2 * (c0 + 2) + 1], (uint32_t)(y0 >> 32));
            }
            if (c0 + 3 < NCHUNK && y1) {
                atomicOr(&removed32[2 * (c0 + 3)],     (uint32_t)y1);
                atomicOr(&removed32[2 * (c0 + 3) + 1], (uint32_t)(y1 >> 32));
            }
            const int n0 = __popcll(keep0), n1 = __popcll(keep1);
            const int base = kept;
            if ((keep0 >> lane) & 1) {
                int p = __popcll(keep0 & ((1ull << lane) - 1ull));
                s_klist[buf][p] = c0 * 64 + lane;
            }
            if ((keep1 >> lane) & 1) {
                int p = n0 + __popcll(keep1 & ((1ull << lane) - 1ull));
                s_klist[buf][p] = c1 * 64 + lane;
            }
            if (lane == 0) {
                s_kmask[c0] = keep0;  s_kmask[c1] = keep1;
                s_kbase[c0] = base;   s_kbase[c1] = base + n0;
                s_k[buf]    = n0 + n1;
                int nk      = base + n0 + n1;
                s_kept      = nk;
                s_nch       = c1 + 1;
                if (nk >= MAX_OUT || it == NTILE - 1) s_done = 1;
            }
            kept += n0 + n1;
        } else if (wave == 1) {
            // ---- prefetch tile it+1 into pf[buf^1] ----
            const int p0 = 2 * it + 2, p1 = 2 * it + 3;
            const int m0 = 2 * it + 4, m1 = 2 * it + 5;
            if (p0 < NCHUNK) {
                pf[buf ^ 1][0][lane] = maskT[(size_t)p0 * N + p0 * 64 + lane];
                pf[buf ^ 1][1][lane] = maskT[(size_t)p1 * N + p1 * 64 + lane];
                pf[buf ^ 1][2][lane] = maskT[(size_t)p1 * N + p0 * 64 + lane];
                if (m0 < NCHUNK) {
                    pf[buf ^ 1][3][lane] = maskT[(size_t)m0 * N + p0 * 64 + lane];
                    pf[buf ^ 1][4][lane] = maskT[(size_t)m0 * N + p1 * 64 + lane];
                    pf[buf ^ 1][5][lane] = maskT[(size_t)m1 * N + p0 * 64 + lane];
                    pf[buf ^ 1][6][lane] = maskT[(size_t)m1 * N + p1 * 64 + lane];
                }
            }
        } else {
            // ---- B: apply tile it-1's kept rows to cols >= 2it+2 ----
            if (it >= 1) {
                const int k = s_k[buf ^ 1];
                const int col = t & 127;           // waves 2..15: 7 groups x 128 cols
                const int g   = (t >> 7) - 1;      // 0..6
                const int colmin = 2 * it + 2;     // cols 2it,2it+1 read-only now;
                                                   // 2it+2,2it+3 covered by A folds too
                if (k > 0 && col >= colmin && col < NCHUNK) {
                    uint64_t v = 0;
                    for (int idx = g; idx < k; idx += 7) {
                        int row = s_klist[buf ^ 1][idx];
                        v |= maskT[(size_t)col * N + row];
                    }
                    if (v) {
                        atomicOr(&removed32[2 * col],     (uint32_t)v);
                        atomicOr(&removed32[2 * col + 1], (uint32_t)(v >> 32));
                    }
                }
            }
        }
        __syncthreads();
        if (s_done) break;
    }

    // ---- parallel output pass ----
    const int nch = s_nch;
    for (int cp = t >> 6; cp < nch; cp += 16) {
        uint64_t km = s_kmask[cp];
        if ((km >> lane) & 1) {
            int pos = s_kbase[cp] + __popcll(km & ((1ull << lane) - 1ull));
            if (pos < MAX_OUT) out[pos] = sidx[cp * 64 + lane];
        }
    }
    const int start = s_kept < MAX_OUT ? s_kept : MAX_OUT;
    for (int p = start + t; p < MAX_OUT; p += 1024) out[p] = -1;
}

// ---------------------------------------------------------------------------
extern "C" void kernel_launch(void* const* d_in, const int* in_sizes, int n_in,
                              void* d_out, int out_size, void* d_ws, size_t ws_size,
                              hipStream_t stream) {
    const float4* rois   = (const float4*)d_in[0];   // [8192,4] fp32
    const float*  scores = (const float*)d_in[1];    // [8192]   fp32
    int* out = (int*)d_out;                          // [300] int32

    // workspace layout (~8.2 MB)
    float4*   sboxes = (float4*)d_ws;                                  // 128 KiB
    int*      sidx   = (int*)((char*)d_ws + 128 * 1024);               //  32 KiB
    uint64_t* maskT  = (uint64_t*)((char*)d_ws + 160 * 1024);          //   8 MiB

    void* args[] = { (void*)&rois, (void*)&scores, (void*)&sboxes,
                     (void*)&sidx, (void*)&maskT, (void*)&out };
    hipLaunchCooperativeKernel((void*)nms_all, dim3(256), dim3(1024),
                               args, 0, stream);
}

// Round 10
// 139.076 us; speedup vs baseline: 1.3890x; 1.3890x over previous
//
#include <hip/hip_runtime.h>
#include <stdint.h>
#include <math.h>

// Must match numpy's unfused fp32 ops exactly: no FMA contraction in this TU.
#pragma clang fp contract(off)

#define N        8192
#define NCHUNK   128      // N / 64
#define TCH      4        // scan: chunks per tile (256 boxes)
#define TNT      (NCHUNK / TCH)   // 32 scan tiles
#define MAX_OUT  300

// ---------------------------------------------------------------------------
// Phase 1a: partial rank counts (R6-proven: same-address LDS broadcasts are
// conflict-free; 1024 blocks -> 16 waves/CU). Comparator: score desc, idx asc
// (unique keys -> ranks are a permutation).
// ---------------------------------------------------------------------------
__global__ void nms_rank_partial(const float* __restrict__ scores,
                                 int* __restrict__ rank32) {
    __shared__ uint32_t sk[256];
    const int tid = threadIdx.x;
    const int bi  = blockIdx.y, bj = blockIdx.x;
    const int jbase = bj * 256;

    sk[tid] = __float_as_uint(scores[jbase + tid]);  // scores >= 0 -> uint-monotonic
    __syncthreads();

    const int i = bi * 256 + tid;
    const uint32_t my = __float_as_uint(scores[i]);

    int cnt = 0;
    const uint4* sk4 = (const uint4*)sk;
    for (int jj = 0; jj < 64; ++jj) {          // same addr across wave: broadcast
        uint4 v = sk4[jj];
        int j0 = jbase + jj * 4;
        cnt += (v.x > my) || (v.x == my && (j0 + 0) < i);
        cnt += (v.y > my) || (v.y == my && (j0 + 1) < i);
        cnt += (v.z > my) || (v.z == my && (j0 + 2) < i);
        cnt += (v.w > my) || (v.w == my && (j0 + 3) < i);
    }
    rank32[bj * N + i] = cnt;
}

// ---------------------------------------------------------------------------
// Phase 1b: sum partials, scatter boxes/indices into score-sorted order.
// ---------------------------------------------------------------------------
__global__ void nms_scatter(const float4* __restrict__ rois,
                            const int*    __restrict__ rank32,
                            float4* __restrict__ sboxes,
                            int*    __restrict__ sidx) {
    const int i = blockIdx.x * blockDim.x + threadIdx.x;
    int r = 0;
#pragma unroll
    for (int k = 0; k < 32; ++k) r += rank32[k * N + i];
    sboxes[r] = rois[i];
    sidx[r]   = i;
}

// ---------------------------------------------------------------------------
// Phase 2: suppression bitmask, transposed layout maskT[colchunk][row].
// 4 INDEPENDENT waves per 256-thread block (per-wave LDS slices, no barrier:
// same-wave LDS write->read is ordered by lgkmcnt) -> 8 blocks/CU = 32
// waves/CU (the 64-thr version capped at 16 workgroups/CU = half the slots).
// Exact f64 compare == fp32 IEEE div vs 0.5:
//   fl32(i/d) > 0.5  <=>  2i > d*(1+2^-24)   (product exact: 24+25 <= 53 bits)
// ---------------------------------------------------------------------------
__global__ void __launch_bounds__(256)
nms_mask(const float4* __restrict__ sboxes,
         uint64_t* __restrict__ maskT) {
    __shared__ float4 rb[4][64];
    __shared__ float  ra[4][64];
    const int lane = threadIdx.x & 63;
    const int w    = threadIdx.x >> 6;
    const int L    = blockIdx.x * 4 + w;         // 2064 blocks x 4 waves = 8256
    if (L >= 8256) return;

    // decode linear tile -> (bi,bj), bj >= bi
    int bi = (int)(128.5 - sqrt(16512.25 - 2.0 * (double)L));
    if (bi < 0) bi = 0;
    if (bi > 127) bi = 127;
    while (bi < 127 && (bi + 1) * 128 - ((bi + 1) * bi) / 2 <= L) ++bi;
    while (bi > 0 && bi * 128 - (bi * (bi - 1)) / 2 > L) --bi;
    const int bj = bi + (L - (bi * 128 - (bi * (bi - 1)) / 2));

    const float4 cb = sboxes[bj * 64 + lane];    // column box (regs)
    const float  ac = (cb.z - cb.x) * (cb.w - cb.y);
    {
        float4 tt = sboxes[bi * 64 + lane];      // row boxes -> own LDS slice
        rb[w][lane] = tt;
        ra[w][lane] = (tt.z - tt.x) * (tt.w - tt.y);
    }
    // no __syncthreads: only this wave reads its slice

    const bool diag = (bi == bj);
    const double C = 1.0 + 0x1p-24;
    uint64_t myword = 0;
    for (int r = 0; r < 64; ++r) {
        const float4 b  = rb[w][r];              // broadcast ds_read
        const float  ar = ra[w][r];
        float lx    = fmaxf(b.x, cb.x);
        float ly    = fmaxf(b.y, cb.y);
        float hx    = fminf(b.z, cb.z);
        float hy    = fminf(b.w, cb.w);
        float wd    = fmaxf(hx - lx, 0.0f);
        float ht    = fmaxf(hy - ly, 0.0f);
        float inter = wd * ht;
        float denom = (ar + ac) - inter;         // left-to-right like numpy
        double di = (double)inter, dd = (double)denom;
        bool sup = (di + di) > (dd * C);         // exact: fl32(di/dd) > 0.5
        uint64_t word = __ballot(sup);
        if (diag)                                // keep only cols > r (uniform)
            word &= (r == 63) ? 0ull : (~0ull << (r + 1));
        myword = (lane == r) ? word : myword;
    }
    maskT[(size_t)bj * N + bi * 64 + lane] = myword;   // 512B coalesced store
}

// ---------------------------------------------------------------------------
// Phase 3: barrier-synced wide-tile scan (R8 structure, rebalanced roles).
// 32 tiles x 4 chunks, ONE __syncthreads per tile.
//  wave 0     : resolve 4 chunks (register readlane chains) + fold next
//               tile's 4 cols.
//  waves 1-11 : prefetch tile t+1 swath (16 KB, 704 lanes -> 2 dwordx4
//               rounds; R8's 192-lane version was the measured bottleneck).
//  waves 12-15: apply tile t-1's kept rows to cols >= 4t+4 (2 row-stripes).
// ---------------------------------------------------------------------------
__device__ __forceinline__ uint64_t rl64(uint64_t v, int l) {
    uint32_t lo = (uint32_t)__builtin_amdgcn_readlane((int)(uint32_t)v, l);
    uint32_t hi = (uint32_t)__builtin_amdgcn_readlane((int)(uint32_t)(v >> 32), l);
    return ((uint64_t)hi << 32) | lo;
}

__global__ void __launch_bounds__(1024)
nms_scan(const uint64_t* __restrict__ maskT,
         const int*      __restrict__ sidx,
         int*            __restrict__ out) {
    __shared__ uint64_t removed[NCHUNK];           // 1 KB
    __shared__ uint64_t pf[2][2 * TCH][64 * TCH];  // 32 KB: [buf][col d][row r]
    __shared__ uint64_t s_kmask[NCHUNK];           // 1 KB
    __shared__ int      s_kbase[NCHUNK];
    __shared__ int      s_klist[2][256];
    __shared__ int      s_kcnt[2];
    __shared__ int      s_done, s_kept, s_nch;

    const int t    = threadIdx.x;
    const int lane = t & 63;
    const int wave = t >> 6;

    if (t < NCHUNK) removed[t] = 0;
    if (t == 0) { s_done = 0; s_kept = 0; s_nch = 0; s_kcnt[0] = 0; s_kcnt[1] = 0; }
    if (wave >= 1 && wave <= 11) {                 // preload tile 0 swath
        const int id = (wave - 1) * 64 + lane;     // 0..703
        for (int p = id; p < 1024; p += 704) {     // 1024 row-pairs (16B each)
            int d = p >> 7, rp = (p & 127) * 2;
            const uint64_t* src = &maskT[(size_t)d * N + rp];
            pf[0][d][rp]     = src[0];
            pf[0][d][rp + 1] = src[1];
        }
    }
    __syncthreads();

    for (int tt = 0; tt < TNT; ++tt) {
        const int c0  = TCH * tt;
        const int buf = tt & 1;

        if (wave == 0) {
            // ---------------- resolver ----------------
            uint64_t rem[TCH];
#pragma unroll
            for (int s = 0; s < TCH; ++s) rem[s] = removed[c0 + s];
            uint64_t y0 = 0, y1 = 0, y2 = 0, y3 = 0;   // folds: cols c0+4..c0+7
            uint64_t keepm[TCH];
            int      n[TCH];
#pragma unroll
            for (int s = 0; s < TCH; ++s) {
                uint64_t D  = pf[buf][s][s * 64 + lane];        // own-chunk diag
                uint64_t A4 = pf[buf][4][s * 64 + lane];
                uint64_t A5 = pf[buf][5][s * 64 + lane];
                uint64_t A6 = pf[buf][6][s * 64 + lane];
                uint64_t A7 = pf[buf][7][s * 64 + lane];
                uint64_t X1 = (s + 1 < TCH) ? pf[buf][s + 1][s * 64 + lane] : 0;
                uint64_t X2 = (s + 2 < TCH) ? pf[buf][s + 2][s * 64 + lane] : 0;
                uint64_t X3 = (s + 3 < TCH) ? pf[buf][s + 3][s * 64 + lane] : 0;
                uint64_t cand = ~rem[s];
                uint64_t keep = 0;
                while (cand) {
                    int l = __builtin_ctzll(cand);
                    keep |= (1ull << l);
                    uint64_t d0 = rl64(D, l);
                    cand &= ~d0;
                    cand &= ~(1ull << l);
                    if (s + 1 < TCH) rem[s + 1] |= rl64(X1, l); // in-tile cross
                    if (s + 2 < TCH) rem[s + 2] |= rl64(X2, l);
                    if (s + 3 < TCH) rem[s + 3] |= rl64(X3, l);
                    y0 |= rl64(A4, l);                           // next-tile folds
                    y1 |= rl64(A5, l);
                    y2 |= rl64(A6, l);
                    y3 |= rl64(A7, l);
                }
                keepm[s] = keep;
                n[s] = __popcll(keep);
            }
            if (lane == 0) {                       // fold writes (y uniform)
                if (y0 && c0 + 4 < NCHUNK) atomicOr((unsigned long long*)&removed[c0 + 4], (unsigned long long)y0);
                if (y1 && c0 + 5 < NCHUNK) atomicOr((unsigned long long*)&removed[c0 + 5], (unsigned long long)y1);
                if (y2 && c0 + 6 < NCHUNK) atomicOr((unsigned long long*)&removed[c0 + 6], (unsigned long long)y2);
                if (y3 && c0 + 7 < NCHUNK) atomicOr((unsigned long long*)&removed[c0 + 7], (unsigned long long)y3);
            }
            int barr[TCH];
            barr[0] = 0;
#pragma unroll
            for (int s = 1; s < TCH; ++s) barr[s] = barr[s - 1] + n[s - 1];
#pragma unroll
            for (int s = 0; s < TCH; ++s) {        // tile-local kept list
                uint64_t km = keepm[s];
                if ((km >> lane) & 1) {
                    int p = barr[s] + __popcll(km & ((1ull << lane) - 1ull));
                    s_klist[buf][p] = (c0 + s) * 64 + lane;
                }
            }
            if (lane == 0) {
                const int kprev = s_kept;
                const int ktile = barr[TCH - 1] + n[TCH - 1];
#pragma unroll
                for (int s = 0; s < TCH; ++s) {
                    s_kmask[c0 + s] = keepm[s];
                    s_kbase[c0 + s] = kprev + barr[s];
                }
                s_kcnt[buf] = ktile;
                s_kept      = kprev + ktile;
                s_nch       = c0 + TCH;
                if (kprev + ktile >= MAX_OUT || tt == TNT - 1) s_done = 1;
            }
        } else if (wave <= 11) {
            // ---------------- prefetch tile tt+1 (704 lanes) ----------------
            const int tp = tt + 1;
            if (tp < TNT) {
                const int c0p = TCH * tp;
                const int id  = (wave - 1) * 64 + lane;
                for (int p = id; p < 1024; p += 704) {
                    int d = p >> 7, rp = (p & 127) * 2;
                    int col = c0p + d;
                    uint64_t v0 = 0, v1 = 0;
                    if (col < NCHUNK) {
                        const uint64_t* src = &maskT[(size_t)col * N + (size_t)c0p * 64 + rp];
                        v0 = src[0]; v1 = src[1];
                    }
                    pf[buf ^ 1][d][rp]     = v0;
                    pf[buf ^ 1][d][rp + 1] = v1;
                }
            }
        } else {
            // ---------------- apply tile tt-1 (waves 12..15) ----------------
            if (tt >= 1) {
                const int sl  = buf ^ 1;           // (tt-1) & 1
                const int k   = s_kcnt[sl];
                const int id  = (wave - 12) * 64 + lane;  // 0..255
                const int col = id & 127;
                const int g   = id >> 7;           // 0..1 row-stripe
                const int colmin = TCH * tt + TCH; // 4tt+4
                if (k > 0 && col >= colmin && col < NCHUNK) {
                    uint64_t v = 0;
                    for (int idx = g; idx < k; idx += 2) {
                        int row = s_klist[sl][idx];
                        v |= maskT[(size_t)col * N + row];
                    }
                    if (v) atomicOr((unsigned long long*)&removed[col], (unsigned long long)v);
                }
            }
        }
        __syncthreads();
        if (s_done) break;
    }

    // ---- parallel output pass ----
    const int nch = s_nch;
    for (int cp = t >> 6; cp < nch; cp += 16) {
        uint64_t km = s_kmask[cp];
        if ((km >> lane) & 1) {
            int pos = s_kbase[cp] + __popcll(km & ((1ull << lane) - 1ull));
            if (pos < MAX_OUT) out[pos] = sidx[cp * 64 + lane];
        }
    }
    const int start = s_kept < MAX_OUT ? s_kept : MAX_OUT;
    for (int p = start + t; p < MAX_OUT; p += 1024) out[p] = -1;
}

// ---------------------------------------------------------------------------
extern "C" void kernel_launch(void* const* d_in, const int* in_sizes, int n_in,
                              void* d_out, int out_size, void* d_ws, size_t ws_size,
                              hipStream_t stream) {
    const float4* rois   = (const float4*)d_in[0];   // [8192,4] fp32
    const float*  scores = (const float*)d_in[1];    // [8192]   fp32
    int* out = (int*)d_out;                          // [300] int32

    // workspace layout (~9.3 MB)
    float4*   sboxes = (float4*)d_ws;                                      // 128 KiB
    int*      sidx   = (int*)((char*)d_ws + 128 * 1024);                   //  32 KiB
    uint64_t* maskT  = (uint64_t*)((char*)d_ws + 160 * 1024);              //   8 MiB
    int*      rank32 = (int*)((char*)d_ws + 160 * 1024 + 8 * 1024 * 1024); //   1 MiB

    nms_rank_partial<<<dim3(32, 32), dim3(256), 0, stream>>>(scores, rank32);
    nms_scatter<<<dim3(32), dim3(256), 0, stream>>>(rois, rank32, sboxes, sidx);
    nms_mask<<<dim3(2064), dim3(256), 0, stream>>>(sboxes, maskT);
    nms_scan<<<dim3(1), dim3(1024), 0, stream>>>(maskT, sidx, out);
}

// Round 11
// 119.481 us; speedup vs baseline: 1.6168x; 1.1640x over previous
//
#include <hip/hip_runtime.h>
#include <stdint.h>
#include <math.h>

// Must match numpy's unfused fp32 ops exactly: no FMA contraction in this TU.
#pragma clang fp contract(off)

#define N        8192
#define NCHUNK   128      // N / 64
#define NTILE    64       // scan: 2 chunks per tile
#define MAX_OUT  300

// ---------------------------------------------------------------------------
// Phase 1a: partial rank counts (conflict-free same-address LDS broadcasts).
// Comparator: score desc, idx asc (unique keys -> ranks are a permutation).
// ---------------------------------------------------------------------------
__global__ void nms_rank_partial(const float* __restrict__ scores,
                                 int* __restrict__ rank32) {
    __shared__ uint32_t sk[256];
    const int tid = threadIdx.x;
    const int bi  = blockIdx.y, bj = blockIdx.x;
    const int jbase = bj * 256;

    sk[tid] = __float_as_uint(scores[jbase + tid]);  // scores >= 0 -> uint-monotonic
    __syncthreads();

    const int i = bi * 256 + tid;
    const uint32_t my = __float_as_uint(scores[i]);

    int cnt = 0;
    const uint4* sk4 = (const uint4*)sk;
    for (int jj = 0; jj < 64; ++jj) {          // same addr across wave: broadcast
        uint4 v = sk4[jj];
        int j0 = jbase + jj * 4;
        cnt += (v.x > my) || (v.x == my && (j0 + 0) < i);
        cnt += (v.y > my) || (v.y == my && (j0 + 1) < i);
        cnt += (v.z > my) || (v.z == my && (j0 + 2) < i);
        cnt += (v.w > my) || (v.w == my && (j0 + 3) < i);
    }
    rank32[bj * N + i] = cnt;
}

// ---------------------------------------------------------------------------
// Phase 1b: sum partials, scatter boxes/indices into score-sorted order.
// ---------------------------------------------------------------------------
__global__ void nms_scatter(const float4* __restrict__ rois,
                            const int*    __restrict__ rank32,
                            float4* __restrict__ sboxes,
                            int*    __restrict__ sidx) {
    const int i = blockIdx.x * blockDim.x + threadIdx.x;
    int r = 0;
#pragma unroll
    for (int k = 0; k < 32; ++k) r += rank32[k * N + i];
    sboxes[r] = rois[i];
    sidx[r]   = i;
}

// ---------------------------------------------------------------------------
// Phase 2: suppression bitmask, transposed layout maskT[colchunk][row].
// 4 independent waves per 256-thread block (per-wave LDS slices, no barrier).
// Exact f64 compare == fp32 IEEE div vs 0.5:
//   fl32(i/d) > 0.5  <=>  2i > d*(1+2^-24)   (product exact: 24+25 <= 53 bits)
// ---------------------------------------------------------------------------
__global__ void __launch_bounds__(256)
nms_mask(const float4* __restrict__ sboxes,
         uint64_t* __restrict__ maskT) {
    __shared__ float4 rb[4][64];
    __shared__ float  ra[4][64];
    const int lane = threadIdx.x & 63;
    const int w    = threadIdx.x >> 6;
    const int L    = blockIdx.x * 4 + w;         // 2064 blocks x 4 waves = 8256
    if (L >= 8256) return;

    // decode linear tile -> (bi,bj), bj >= bi
    int bi = (int)(128.5 - sqrt(16512.25 - 2.0 * (double)L));
    if (bi < 0) bi = 0;
    if (bi > 127) bi = 127;
    while (bi < 127 && (bi + 1) * 128 - ((bi + 1) * bi) / 2 <= L) ++bi;
    while (bi > 0 && bi * 128 - (bi * (bi - 1)) / 2 > L) --bi;
    const int bj = bi + (L - (bi * 128 - (bi * (bi - 1)) / 2));

    const float4 cb = sboxes[bj * 64 + lane];    // column box (regs)
    const float  ac = (cb.z - cb.x) * (cb.w - cb.y);
    {
        float4 tt = sboxes[bi * 64 + lane];      // row boxes -> own LDS slice
        rb[w][lane] = tt;
        ra[w][lane] = (tt.z - tt.x) * (tt.w - tt.y);
    }
    // no __syncthreads: only this wave reads its slice (lgkmcnt orders it)

    const bool diag = (bi == bj);
    const double C = 1.0 + 0x1p-24;
    uint64_t myword = 0;
    for (int r = 0; r < 64; ++r) {
        const float4 b  = rb[w][r];              // broadcast ds_read
        const float  ar = ra[w][r];
        float lx    = fmaxf(b.x, cb.x);
        float ly    = fmaxf(b.y, cb.y);
        float hx    = fminf(b.z, cb.z);
        float hy    = fminf(b.w, cb.w);
        float wd    = fmaxf(hx - lx, 0.0f);
        float ht    = fmaxf(hy - ly, 0.0f);
        float inter = wd * ht;
        float denom = (ar + ac) - inter;         // left-to-right like numpy
        double di = (double)inter, dd = (double)denom;
        bool sup = (di + di) > (dd * C);         // exact: fl32(di/dd) > 0.5
        uint64_t word = __ballot(sup);
        if (diag)                                // keep only cols > r (uniform)
            word &= (r == 63) ? 0ull : (~0ull << (r + 1));
        myword = (lane == r) ? word : myword;
    }
    maskT[(size_t)bj * N + bi * 64 + lane] = myword;   // 512B coalesced store
}

// ---------------------------------------------------------------------------
// Phase 3: greedy scan — R6-design verbatim (measured 9.6 us in R6).
// 64 tiles x 2 chunks, ONE __syncthreads per tile.
//  wave 0  : resolve tile it (register readlane chains) + fold cols +2/+3.
//  wave 1  : prefetch tile it+1 words (D0,D1,X,Y0a,Y0b,Y1a,Y1b) into LDS dbuf.
//  waves 2-15: apply tile it-1's kept rows to cols >= 2it+2 (7-way striped).
// ---------------------------------------------------------------------------
__device__ __forceinline__ uint64_t rl64(uint64_t v, int l) {
    uint32_t lo = (uint32_t)__builtin_amdgcn_readlane((int)(uint32_t)v, l);
    uint32_t hi = (uint32_t)__builtin_amdgcn_readlane((int)(uint32_t)(v >> 32), l);
    return ((uint64_t)hi << 32) | lo;
}

__global__ void __launch_bounds__(1024)
nms_scan(const uint64_t* __restrict__ maskT,
         const int*      __restrict__ sidx,
         int*            __restrict__ out) {
    __shared__ uint32_t removed32[2 * NCHUNK];   // per-chunk removed, lo/hi pairs
    __shared__ uint64_t pf[2][7][64];            // dbuf: D0,D1,X,Y0a,Y0b,Y1a,Y1b
    __shared__ uint64_t s_kmask[NCHUNK];
    __shared__ int      s_kbase[NCHUNK];
    __shared__ int      s_klist[2][128];
    __shared__ int      s_k[2];
    __shared__ int      s_kept, s_done, s_nch;

    const int t    = threadIdx.x;
    const int lane = t & 63;
    const int wave = t >> 6;

    if (t < 2 * NCHUNK) removed32[t] = 0;
    if (t == 0) { s_kept = 0; s_done = 0; s_nch = 0; s_k[0] = 0; s_k[1] = 0; }
    if (wave == 1) {                             // prefetch tile 0 into pf[0]
        pf[0][0][lane] = maskT[(size_t)0 * N + 0 * 64 + lane];   // D0
        pf[0][1][lane] = maskT[(size_t)1 * N + 1 * 64 + lane];   // D1
        pf[0][2][lane] = maskT[(size_t)1 * N + 0 * 64 + lane];   // X
        pf[0][3][lane] = maskT[(size_t)2 * N + 0 * 64 + lane];   // Y0a
        pf[0][4][lane] = maskT[(size_t)2 * N + 1 * 64 + lane];   // Y0b
        pf[0][5][lane] = maskT[(size_t)3 * N + 0 * 64 + lane];   // Y1a
        pf[0][6][lane] = maskT[(size_t)3 * N + 1 * 64 + lane];   // Y1b
    }
    __syncthreads();

    int kept = 0;                                // wave0-uniform mirror of s_kept
    for (int it = 0; it < NTILE; ++it) {
        const int c0 = 2 * it, c1 = 2 * it + 1;
        const int buf = it & 1;

        if (wave == 0) {
            // ---- A: resolve tile it ----
            uint64_t D0  = pf[buf][0][lane], D1  = pf[buf][1][lane];
            uint64_t X   = pf[buf][2][lane];
            uint64_t Y0a = pf[buf][3][lane], Y0b = pf[buf][4][lane];
            uint64_t Y1a = pf[buf][5][lane], Y1b = pf[buf][6][lane];
            uint64_t rem0 = (uint64_t)removed32[2 * c0] | ((uint64_t)removed32[2 * c0 + 1] << 32);
            uint64_t rem1 = (uint64_t)removed32[2 * c1] | ((uint64_t)removed32[2 * c1 + 1] << 32);
            uint64_t keep0 = 0, keep1 = 0, xw = 0, y0 = 0, y1 = 0;

            uint64_t cand = ~rem0;                 // chunk c0 greedy chain
            while (cand) {
                int l = __builtin_ctzll(cand);
                keep0 |= (1ull << l);
                uint64_t d = rl64(D0, l);
                xw |= rl64(X, l);
                y0 |= rl64(Y0a, l);
                y1 |= rl64(Y1a, l);
                cand &= ~d;
                cand &= ~(1ull << l);
            }
            rem1 |= xw;
            cand = ~rem1;                          // chunk c1 greedy chain
            while (cand) {
                int l = __builtin_ctzll(cand);
                keep1 |= (1ull << l);
                uint64_t d = rl64(D1, l);
                y0 |= rl64(Y0b, l);
                y1 |= rl64(Y1b, l);
                cand &= ~d;
                cand &= ~(1ull << l);
            }
            // fold urgent removed-updates for next tile (atomic: B also writes)
            if (c0 + 2 < NCHUNK && y0) {
                atomicOr(&removed32[2 * (c0 + 2)],     (uint32_t)y0);
                atomicOr(&removed32[2 * (c0 + 2) + 1], (uint32_t)(y0 >> 32));
            }
            if (c0 + 3 < NCHUNK && y1) {
                atomicOr(&removed32[2 * (c0 + 3)],     (uint32_t)y1);
                atomicOr(&removed32[2 * (c0 + 3) + 1], (uint32_t)(y1 >> 32));
            }
            const int n0 = __popcll(keep0), n1 = __popcll(keep1);
            const int base = kept;
            if ((keep0 >> lane) & 1) {
                int p = __popcll(keep0 & ((1ull << lane) - 1ull));
                s_klist[buf][p] = c0 * 64 + lane;
            }
            if ((keep1 >> lane) & 1) {
                int p = n0 + __popcll(keep1 & ((1ull << lane) - 1ull));
                s_klist[buf][p] = c1 * 64 + lane;
            }
            if (lane == 0) {
                s_kmask[c0] = keep0;  s_kmask[c1] = keep1;
                s_kbase[c0] = base;   s_kbase[c1] = base + n0;
                s_k[buf]    = n0 + n1;
                int nk      = base + n0 + n1;
                s_kept      = nk;
                s_nch       = c1 + 1;
                if (nk >= MAX_OUT || it == NTILE - 1) s_done = 1;
            }
            kept += n0 + n1;
        } else if (wave == 1) {
            // ---- prefetch tile it+1 into pf[buf^1] ----
            const int p0 = 2 * it + 2, p1 = 2 * it + 3;
            const int m0 = 2 * it + 4, m1 = 2 * it + 5;
            if (p0 < NCHUNK) {
                pf[buf ^ 1][0][lane] = maskT[(size_t)p0 * N + p0 * 64 + lane];
                pf[buf ^ 1][1][lane] = maskT[(size_t)p1 * N + p1 * 64 + lane];
                pf[buf ^ 1][2][lane] = maskT[(size_t)p1 * N + p0 * 64 + lane];
                if (m0 < NCHUNK) {
                    pf[buf ^ 1][3][lane] = maskT[(size_t)m0 * N + p0 * 64 + lane];
                    pf[buf ^ 1][4][lane] = maskT[(size_t)m0 * N + p1 * 64 + lane];
                    pf[buf ^ 1][5][lane] = maskT[(size_t)m1 * N + p0 * 64 + lane];
                    pf[buf ^ 1][6][lane] = maskT[(size_t)m1 * N + p1 * 64 + lane];
                }
            }
        } else {
            // ---- B: apply tile it-1's kept rows to cols >= 2it+2 ----
            if (it >= 1) {
                const int k = s_k[buf ^ 1];
                const int col = t & 127;           // waves 2..15: 7 groups x 128 cols
                const int g   = (t >> 7) - 1;      // 0..6
                const int colmin = 2 * it + 2;     // cols 2it,2it+1 read-only now;
                                                   // 2it+2,2it+3 covered by A folds too
                if (k > 0 && col >= colmin && col < NCHUNK) {
                    uint64_t v = 0;
                    for (int idx = g; idx < k; idx += 7) {
                        int row = s_klist[buf ^ 1][idx];
                        v |= maskT[(size_t)col * N + row];
                    }
                    if (v) {
                        atomicOr(&removed32[2 * col],     (uint32_t)v);
                        atomicOr(&removed32[2 * col + 1], (uint32_t)(v >> 32));
                    }
                }
            }
        }
        __syncthreads();
        if (s_done) break;
    }

    // ---- parallel output pass ----
    const int nch = s_nch;
    for (int cp = t >> 6; cp < nch; cp += 16) {
        uint64_t km = s_kmask[cp];
        if ((km >> lane) & 1) {
            int pos = s_kbase[cp] + __popcll(km & ((1ull << lane) - 1ull));
            if (pos < MAX_OUT) out[pos] = sidx[cp * 64 + lane];
        }
    }
    const int start = s_kept < MAX_OUT ? s_kept : MAX_OUT;
    for (int p = start + t; p < MAX_OUT; p += 1024) out[p] = -1;
}

// ---------------------------------------------------------------------------
extern "C" void kernel_launch(void* const* d_in, const int* in_sizes, int n_in,
                              void* d_out, int out_size, void* d_ws, size_t ws_size,
                              hipStream_t stream) {
    const float4* rois   = (const float4*)d_in[0];   // [8192,4] fp32
    const float*  scores = (const float*)d_in[1];    // [8192]   fp32
    int* out = (int*)d_out;                          // [300] int32

    // workspace layout (~9.3 MB)
    float4*   sboxes = (float4*)d_ws;                                      // 128 KiB
    int*      sidx   = (int*)((char*)d_ws + 128 * 1024);                   //  32 KiB
    uint64_t* maskT  = (uint64_t*)((char*)d_ws + 160 * 1024);              //   8 MiB
    int*      rank32 = (int*)((char*)d_ws + 160 * 1024 + 8 * 1024 * 1024); //   1 MiB

    nms_rank_partial<<<dim3(32, 32), dim3(256), 0, stream>>>(scores, rank32);
    nms_scatter<<<dim3(32), dim3(256), 0, stream>>>(rois, rank32, sboxes, sidx);
    nms_mask<<<dim3(2064), dim3(256), 0, stream>>>(sboxes, maskT);
    nms_scan<<<dim3(1), dim3(1024), 0, stream>>>(maskT, sidx, out);
}